// Round 13
// baseline (171.610 us; speedup 1.0000x reference)
//
#include <hip/hip_runtime.h>

// SupProtoConLoss on MI355X — round 24: consolidation (R23 loop + fused fast
// finisher, 2 nodes).
// League: R16 147.5 (3-node, k_row 78.9); R23 147.2 (3-node, k_row 79.1,
// conflicts 0). R23 post-mortem: counted-vmcnt with ~11.7k cy of cover
// changed NOTHING vs drain-every-iter => the drain was never the limiter;
// 5 structural loop variants converge at 78-81us with every pipe <=35% =>
// latency/issue plateau at 16 waves/CU (LDS caps TLP: 2-buf 128^2 = 32KB+
// => 4 blk/CU max). Remaining addressable time is node overhead:
// 3-node = k_row + ~64-68us, 2-node = k_row + ~59us. R21's fused finisher
// lost only via 64 ORDERED agent-atomic loads (~13us); R20 proved the fast
// form (one __threadfence + float4 loads, absmax 0). R24 = R23 k_row
// verbatim + last-block-done + R20 finisher; k_final node dropped.

#define NROW 8192
#define DDIM 512
#define NCLS 100
#define TILE 128
#define BK 32
#define NKS 16     // DDIM / BK
#define NTRI 2080  // 64*65/2 triangle tiles

typedef float f32x4 __attribute__((ext_vector_type(4)));
typedef short s16x8 __attribute__((ext_vector_type(8)));

#define GLOBAL_AS __attribute__((address_space(1)))
#define LDS_AS __attribute__((address_space(3)))

__device__ __forceinline__ unsigned short f2bf(float x) {
  unsigned int u = __builtin_bit_cast(unsigned int, x);
  u += 0x7FFFu + ((u >> 16) & 1u);  // round-to-nearest-even
  return (unsigned short)(u >> 16);
}

// One wave per row: L2-norm, scale, cast to bf16. Also zeroes row_pos/row_neg
// and the done-counter — k_row only touches them afterwards.
__global__ void __launch_bounds__(256) k_prep(
    const float* __restrict__ reps, float* __restrict__ row_pos,
    unsigned short* __restrict__ Rb, unsigned* __restrict__ cnt) {
  const int wave = threadIdx.x >> 6;
  const int lane = threadIdx.x & 63;
  const int row = blockIdx.x * 4 + wave;
  if (threadIdx.x < 8) row_pos[blockIdx.x * 8 + threadIdx.x] = 0.0f;
  if (blockIdx.x == 0 && threadIdx.x == 0) cnt[0] = 0u;
  const float* r = reps + (size_t)row * DDIM;
  float4 v0 = *(const float4*)(r + lane * 4);
  float4 v1 = *(const float4*)(r + 256 + lane * 4);
  float ss = v0.x * v0.x + v0.y * v0.y + v0.z * v0.z + v0.w * v0.w +
             v1.x * v1.x + v1.y * v1.y + v1.z * v1.z + v1.w * v1.w;
#pragma unroll
  for (int m = 1; m < 64; m <<= 1) ss += __shfl_xor(ss, m);
  const float scale = 1.0f / sqrtf(ss);  // norms ~22.6; 1e-8 clamp unreachable
  ushort4 a, b;
  a.x = f2bf(v0.x * scale); a.y = f2bf(v0.y * scale);
  a.z = f2bf(v0.z * scale); a.w = f2bf(v0.w * scale);
  b.x = f2bf(v1.x * scale); b.y = f2bf(v1.y * scale);
  b.z = f2bf(v1.z * scale); b.w = f2bf(v1.w * scale);
  *(ushort4*)(Rb + (size_t)row * DDIM + lane * 4) = a;
  *(ushort4*)(Rb + (size_t)row * DDIM + 256 + lane * 4) = b;
}

// Block = one upper-triangle 128x128 tile (tm <= tn), sqrt decode.
// 4 waves as 2M x 2N; wave tile 64x64 = acc[4][4] of 16x16x32.
// LDS shorts: A bufs 3 x 4096 at 0; B bufs 2 x 4096 at 12288. Pair-row map:
// phys 16B-unit u -> {pr=u>>3, ps=u&7, sp=ps^(pr&7), row=2pr+(sp>>2),
// slot=sp&3}; read ps=(quad+4*(c16&1))^(c16>>1) => 2 lanes/bank, no conflict.
__global__ void __launch_bounds__(256, 4) k_row(
    const unsigned short* __restrict__ Rb, const int* __restrict__ labels,
    float* __restrict__ row_pos, float* __restrict__ row_neg,
    unsigned* __restrict__ cnt, float* __restrict__ out) {
  const int t = blockIdx.x;
  int tn = (int)((sqrtf(8.0f * (float)t + 1.0f) - 1.0f) * 0.5f);
  while ((tn + 1) * (tn + 2) / 2 <= t) ++tn;
  while (tn * (tn + 1) / 2 > t) --tn;
  const int tm = t - tn * (tn + 1) / 2;  // 0..tn
  const int i0 = tm * TILE;
  const int j0 = tn * TILE;
  const bool diag = (tm == tn);

  __shared__ __attribute__((aligned(16))) unsigned short LDSH[20480];  // 40KB
  unsigned short* LF = LDSH;
  __shared__ unsigned flg;

  const int tid = threadIdx.x;
  const int lane = tid & 63;
  const int wave = tid >> 6;  // 0..3
  const int wr = wave >> 1, wc = wave & 1;
  const int quad = lane >> 4, c16 = lane & 15;

  // staging source bases (pair-row map), per lane, 2 units per wave per mat.
  unsigned sbA[2], sbB[2];
#pragma unroll
  for (int tt = 0; tt < 2; ++tt) {
    const unsigned u = wave * 128 + tt * 64 + lane;  // 16B unit in mat tile
    const unsigned pr = u >> 3, ps = u & 7;
    const unsigned sp = ps ^ (pr & 7);
    const unsigned rr = pr * 2 + (sp >> 2);
    const unsigned sl = (sp & 3) * 8;
    sbA[tt] = (unsigned)(i0 + rr) * DDIM + sl;
    sbB[tt] = (unsigned)(j0 + rr) * DDIM + sl;
  }
  const int dstu = wave * 128 * 8;  // wave's dest base within a buf (shorts)

  auto stageA = [&](int kt2, int ab) {  // 2 loads/wave
    const int koff = kt2 * BK;
#pragma unroll
    for (int tt = 0; tt < 2; ++tt) {
      const unsigned short* src = Rb + sbA[tt] + koff;
      __builtin_amdgcn_global_load_lds(
          (GLOBAL_AS void*)const_cast<unsigned short*>(src),
          (LDS_AS void*)(LF + ab * 4096 + dstu + tt * 512), 16, 0, 0);
    }
  };
  auto stageB = [&](int kt2, int bb) {  // 2 loads/wave
    const int koff = kt2 * BK;
#pragma unroll
    for (int tt = 0; tt < 2; ++tt) {
      const unsigned short* src = Rb + sbB[tt] + koff;
      __builtin_amdgcn_global_load_lds(
          (GLOBAL_AS void*)const_cast<unsigned short*>(src),
          (LDS_AS void*)(LF + 12288 + bb * 4096 + dstu + tt * 512), 16, 0, 0);
    }
  };

  // frag read bases (pair-row map), within one 4096-short buf.
  const int c16h = c16 >> 1;
  const int psr = (quad + 4 * (c16 & 1)) ^ c16h;
  const int aRel = wr * 2048 + c16h * 64 + psr * 8;
  const int bRel = wc * 2048 + c16h * 64 + psr * 8;

  f32x4 acc[4][4];
#pragma unroll
  for (int m = 0; m < 4; ++m)
#pragma unroll
    for (int n = 0; n < 4; ++n) acc[m][n] = (f32x4)0.0f;

  // Prologue: B(0), A(0), A(1). Per-wave FIFO: B0_2 A0_2 A1_2 -> vmcnt(2)
  // waits {B0,A0}, leaves A1 in flight.
  stageB(0, 0);
  stageA(0, 0);
  stageA(1, 1);
  __builtin_amdgcn_sched_barrier(0);
  asm volatile("s_waitcnt vmcnt(2)" ::: "memory");
  __builtin_amdgcn_s_barrier();

  int ca = 0;  // kt % 3 (A buf of current kt)
#pragma unroll 1
  for (int kt = 0; kt < NKS; ++kt) {
    // issue order matters for the vmcnt ledger: B(kt+1) then A(kt+2).
    if (kt + 1 < NKS) stageB(kt + 1, (kt + 1) & 1);
    if (kt + 2 < NKS) stageA(kt + 2, ca >= 1 ? ca - 1 : ca + 2);  // (kt+2)%3

    const int aOff = ca * 4096;
    const int bOff = 12288 + (kt & 1) * 4096;
    s16x8 af[4], bf[4];
#pragma unroll
    for (int m = 0; m < 4; ++m)
      af[m] = *(const s16x8*)(LF + aOff + aRel + m * 512);
#pragma unroll
    for (int n = 0; n < 4; ++n)
      bf[n] = *(const s16x8*)(LF + bOff + bRel + n * 512);
#pragma unroll
    for (int m = 0; m < 4; ++m)
#pragma unroll
      for (int n = 0; n < 4; ++n)
        acc[m][n] = __builtin_amdgcn_mfma_f32_16x16x32_bf16(af[m], bf[n],
                                                            acc[m][n], 0, 0, 0);
    __builtin_amdgcn_sched_barrier(0);
    // Ledger at fence: A(kt+1)2 | B(kt+1)2 | A(kt+2)2 -> vmcnt(2) covers
    // exactly {A(kt+1), B(kt+1)}; A(kt+2) stays in flight ~2 iters.
    if (kt <= NKS - 3) {
      asm volatile("s_waitcnt vmcnt(2)" ::: "memory");
    } else if (kt == NKS - 2) {
      asm volatile("s_waitcnt vmcnt(0)" ::: "memory");
    }
    __builtin_amdgcn_s_barrier();
    ca = ca == 2 ? 0 : ca + 1;
  }

  // ---- Epilogue: fold tile into row-i sums and (off-diag) row-j sums.
  float* rp = (float*)(void*)LF;  // 128 rpos | 128 rneg | 128 cpos | 128 cneg
  float* rn = rp + 128;
  float* cp = rn + 128;
  float* cn = cp + 128;
  rp[tid] = 0.0f;
  rp[tid + 256] = 0.0f;
  __syncthreads();

  const float C0 = -5.0f + 1e-7f;  // s = 5g - 5 + 1e-7 (static shift S=10)
  int lj4[4], gj4[4];
#pragma unroll
  for (int n = 0; n < 4; ++n) {
    gj4[n] = j0 + wc * 64 + n * 16 + c16;
    lj4[n] = labels[gj4[n]];
  }
  float psj[4] = {0.0f, 0.0f, 0.0f, 0.0f};
  float nsj[4] = {0.0f, 0.0f, 0.0f, 0.0f};
#pragma unroll
  for (int m = 0; m < 4; ++m) {
#pragma unroll
    for (int r = 0; r < 4; ++r) {
      const int lrow = wr * 64 + m * 16 + quad * 4 + r;
      const int gi = i0 + lrow;
      const int li = labels[gi];
      float psi = 0.0f, nsi = 0.0f;
#pragma unroll
      for (int n = 0; n < 4; ++n) {
        const float g2 = acc[m][n][r];
        const float sv = fmaf(g2, 5.0f, C0);
        const float ev = __expf(sv);
        const bool same = (li == lj4[n]);
        const bool ok = same && (gi != gj4[n]);
        psi += ok ? sv : 0.0f;
        nsi += same ? 0.0f : ev;
        psj[n] += ok ? sv : 0.0f;  // col-side accumulation (over m,r)
        nsj[n] += same ? 0.0f : ev;
      }
#pragma unroll
      for (int s = 1; s < 16; s <<= 1) {  // reduce over the 16 c16 lanes
        psi += __shfl_xor(psi, s);
        nsi += __shfl_xor(nsi, s);
      }
      if (c16 == 0) {
        atomicAdd(&rp[lrow], psi);
        atomicAdd(&rn[lrow], nsi);
      }
    }
  }
  if (!diag) {  // col-side: reduce over quad groups, cross-wr via LDS atomics
#pragma unroll
    for (int n = 0; n < 4; ++n) {
      float p = psj[n], q = nsj[n];
      p += __shfl_xor(p, 16); p += __shfl_xor(p, 32);
      q += __shfl_xor(q, 16); q += __shfl_xor(q, 32);
      if (quad == 0) {
        atomicAdd(&cp[wc * 64 + n * 16 + c16], p);
        atomicAdd(&cn[wc * 64 + n * 16 + c16], q);
      }
    }
  }
  __syncthreads();
  if (tid < 128) {
    atomicAdd(&row_pos[i0 + tid], rp[tid]);
    atomicAdd(&row_neg[i0 + tid], rn[tid]);
  } else if (!diag) {
    atomicAdd(&row_pos[j0 + tid - 128], cp[tid - 128]);
    atomicAdd(&row_neg[j0 + tid - 128], cn[tid - 128]);
  }
  __syncthreads();  // vmcnt(0): this block's device-scope RMWs all acked

  // ---- last-block-done finisher (R20's fast form, proven absmax 0).
  if (tid == 0) flg = atomicAdd(cnt, 1u);
  __syncthreads();
  if (flg != NTRI - 1) return;

  // ONE acquire fence (drop stale lines) -> plain pipelined float4 loads are
  // coherent with the producers' coherence-point RMWs. (R18's mistake was
  // 2080 of these mid-flight; a single one at kernel end is free.)
  __threadfence();

  int* hcnt = (int*)(void*)LF;  // reuse LDS: 100 ints
  float* fs = (float*)(void*)LF + 128;
  float* fc = fs + 8;
  if (tid < NCLS) hcnt[tid] = 0;
  __syncthreads();
  for (int i = tid; i < NROW; i += 256) atomicAdd(&hcnt[labels[i]], 1);
  __syncthreads();
  float lsum = 0.0f, lcnt = 0.0f;
  const float4* rp4 = (const float4*)row_pos;
  const float4* rn4 = (const float4*)row_neg;
#pragma unroll 2
  for (int i = tid; i < NROW / 4; i += 256) {
    const float4 p4 = rp4[i];
    const float4 n4 = rn4[i];
    const float pv[4] = {p4.x, p4.y, p4.z, p4.w};
    const float nv[4] = {n4.x, n4.y, n4.z, n4.w};
#pragma unroll
    for (int e = 0; e < 4; ++e) {
      const int row = i * 4 + e;
      const float c = (float)(hcnt[labels[row]] - 1);
      const float pos = pv[e] / (c + 1e-8f);
      const float loss = -pos + logf(nv[e] + 1e-8f);
      if (loss > 0.0f) { lsum += loss; lcnt += 1.0f; }
    }
  }
#pragma unroll
  for (int m = 1; m < 64; m <<= 1) {
    lsum += __shfl_xor(lsum, m);
    lcnt += __shfl_xor(lcnt, m);
  }
  if (lane == 0) { fs[wave] = lsum; fc[wave] = lcnt; }
  __syncthreads();
  if (tid == 0) {
    float S = 0.0f, C = 0.0f;
#pragma unroll
    for (int w = 0; w < 4; ++w) { S += fs[w]; C += fc[w]; }
    out[0] = S / (C + 1e-8f);
  }
}

extern "C" void kernel_launch(void* const* d_in, const int* in_sizes, int n_in,
                              void* d_out, int out_size, void* d_ws, size_t ws_size,
                              hipStream_t stream) {
  const float* reps = (const float*)d_in[0];
  const int* labels = (const int*)d_in[1];
  float* out = (float*)d_out;
  char* ws = (char*)d_ws;
  // ws layout: Rb (bf16 normalized reps, 8 MiB) | row_pos | row_neg | cnt
  unsigned short* Rb = (unsigned short*)ws;
  float* row_pos = (float*)(ws + (size_t)NROW * DDIM * 2);
  float* row_neg = row_pos + NROW;
  unsigned* cnt = (unsigned*)(row_neg + NROW);

  k_prep<<<NROW / 4, 256, 0, stream>>>(reps, row_pos, Rb, cnt);
  k_row<<<NTRI, 256, 0, stream>>>(Rb, labels, row_pos, row_neg, cnt, out);
  (void)in_sizes; (void)n_in; (void)out_size; (void)ws_size;
}

// Round 14
// 145.225 us; speedup vs baseline: 1.1817x; 1.1817x over previous
//
#include <hip/hip_runtime.h>

// SupProtoConLoss on MI355X — round 26: lock R23 (league best, 147.2), trim
// only the isolated side kernels.
// League: R23 147.2 (k_row 79.1, conflicts 0); R24 fused finisher REGRESSED
// (171.6): extra __shared__ flg -> LDS 41472 broke the exact 4-blk/CU fit,
// VGPR 64->108 from finisher inlining; occupancy 32->17. Finisher fusion is
// 0-for-3 (R21 tail 13us, R24 codegen) — closed. Loop is a verified plateau:
// 5 structural variants at 78-81us, all pipes <=35%.
// R26: k_row VERBATIM from R23. k_prep 8 rows/block (1024 blocks, same
// vectorization). k_final 1024 threads (8 strided iters instead of 16).

#define NROW 8192
#define DDIM 512
#define NCLS 100
#define TILE 128
#define BK 32
#define NKS 16     // DDIM / BK
#define NTRI 2080  // 64*65/2 triangle tiles

typedef float f32x4 __attribute__((ext_vector_type(4)));
typedef short s16x8 __attribute__((ext_vector_type(8)));

#define GLOBAL_AS __attribute__((address_space(1)))
#define LDS_AS __attribute__((address_space(3)))

__device__ __forceinline__ unsigned short f2bf(float x) {
  unsigned int u = __builtin_bit_cast(unsigned int, x);
  u += 0x7FFFu + ((u >> 16) & 1u);  // round-to-nearest-even
  return (unsigned short)(u >> 16);
}

// Two rows per wave: L2-norm, scale, cast to bf16. Also zeroes
// row_pos/row_neg (16384 floats over 1024 blocks).
__global__ void __launch_bounds__(256) k_prep(
    const float* __restrict__ reps, float* __restrict__ row_pos,
    unsigned short* __restrict__ Rb) {
  const int wave = threadIdx.x >> 6;
  const int lane = threadIdx.x & 63;
  if (threadIdx.x < 16) row_pos[blockIdx.x * 16 + threadIdx.x] = 0.0f;
#pragma unroll
  for (int rr = 0; rr < 2; ++rr) {
    const int row = blockIdx.x * 8 + wave * 2 + rr;
    const float* r = reps + (size_t)row * DDIM;
    float4 v0 = *(const float4*)(r + lane * 4);
    float4 v1 = *(const float4*)(r + 256 + lane * 4);
    float ss = v0.x * v0.x + v0.y * v0.y + v0.z * v0.z + v0.w * v0.w +
               v1.x * v1.x + v1.y * v1.y + v1.z * v1.z + v1.w * v1.w;
#pragma unroll
    for (int m = 1; m < 64; m <<= 1) ss += __shfl_xor(ss, m);
    const float scale = 1.0f / sqrtf(ss);  // norms ~22.6; clamp unreachable
    ushort4 a, b;
    a.x = f2bf(v0.x * scale); a.y = f2bf(v0.y * scale);
    a.z = f2bf(v0.z * scale); a.w = f2bf(v0.w * scale);
    b.x = f2bf(v1.x * scale); b.y = f2bf(v1.y * scale);
    b.z = f2bf(v1.z * scale); b.w = f2bf(v1.w * scale);
    *(ushort4*)(Rb + (size_t)row * DDIM + lane * 4) = a;
    *(ushort4*)(Rb + (size_t)row * DDIM + 256 + lane * 4) = b;
  }
}

// Block = one upper-triangle 128x128 tile (tm <= tn), sqrt decode.
// 4 waves as 2M x 2N; wave tile 64x64 = acc[4][4] of 16x16x32.
// LDS shorts: A bufs 3 x 4096 at 0; B bufs 2 x 4096 at 12288. Pair-row map:
// phys 16B-unit u -> {pr=u>>3, ps=u&7, sp=ps^(pr&7), row=2pr+(sp>>2),
// slot=sp&3}; read ps=(quad+4*(c16&1))^(c16>>1) => 2 lanes/bank, no conflict.
__global__ void __launch_bounds__(256, 4) k_row(
    const unsigned short* __restrict__ Rb, const int* __restrict__ labels,
    float* __restrict__ row_pos, float* __restrict__ row_neg) {
  const int t = blockIdx.x;
  int tn = (int)((sqrtf(8.0f * (float)t + 1.0f) - 1.0f) * 0.5f);
  while ((tn + 1) * (tn + 2) / 2 <= t) ++tn;
  while (tn * (tn + 1) / 2 > t) --tn;
  const int tm = t - tn * (tn + 1) / 2;  // 0..tn
  const int i0 = tm * TILE;
  const int j0 = tn * TILE;
  const bool diag = (tm == tn);

  __shared__ __attribute__((aligned(16))) unsigned short LDSH[20480];  // 40KB
  unsigned short* LF = LDSH;

  const int tid = threadIdx.x;
  const int lane = tid & 63;
  const int wave = tid >> 6;  // 0..3
  const int wr = wave >> 1, wc = wave & 1;
  const int quad = lane >> 4, c16 = lane & 15;

  // staging source bases (pair-row map), per lane, 2 units per wave per mat.
  unsigned sbA[2], sbB[2];
#pragma unroll
  for (int tt = 0; tt < 2; ++tt) {
    const unsigned u = wave * 128 + tt * 64 + lane;  // 16B unit in mat tile
    const unsigned pr = u >> 3, ps = u & 7;
    const unsigned sp = ps ^ (pr & 7);
    const unsigned rr = pr * 2 + (sp >> 2);
    const unsigned sl = (sp & 3) * 8;
    sbA[tt] = (unsigned)(i0 + rr) * DDIM + sl;
    sbB[tt] = (unsigned)(j0 + rr) * DDIM + sl;
  }
  const int dstu = wave * 128 * 8;  // wave's dest base within a buf (shorts)

  auto stageA = [&](int kt2, int ab) {  // 2 loads/wave
    const int koff = kt2 * BK;
#pragma unroll
    for (int tt = 0; tt < 2; ++tt) {
      const unsigned short* src = Rb + sbA[tt] + koff;
      __builtin_amdgcn_global_load_lds(
          (GLOBAL_AS void*)const_cast<unsigned short*>(src),
          (LDS_AS void*)(LF + ab * 4096 + dstu + tt * 512), 16, 0, 0);
    }
  };
  auto stageB = [&](int kt2, int bb) {  // 2 loads/wave
    const int koff = kt2 * BK;
#pragma unroll
    for (int tt = 0; tt < 2; ++tt) {
      const unsigned short* src = Rb + sbB[tt] + koff;
      __builtin_amdgcn_global_load_lds(
          (GLOBAL_AS void*)const_cast<unsigned short*>(src),
          (LDS_AS void*)(LF + 12288 + bb * 4096 + dstu + tt * 512), 16, 0, 0);
    }
  };

  // frag read bases (pair-row map), within one 4096-short buf.
  const int c16h = c16 >> 1;
  const int psr = (quad + 4 * (c16 & 1)) ^ c16h;
  const int aRel = wr * 2048 + c16h * 64 + psr * 8;
  const int bRel = wc * 2048 + c16h * 64 + psr * 8;

  f32x4 acc[4][4];
#pragma unroll
  for (int m = 0; m < 4; ++m)
#pragma unroll
    for (int n = 0; n < 4; ++n) acc[m][n] = (f32x4)0.0f;

  // Prologue: B(0), A(0), A(1). Per-wave FIFO: B0_2 A0_2 A1_2 -> vmcnt(2)
  // waits {B0,A0}, leaves A1 in flight.
  stageB(0, 0);
  stageA(0, 0);
  stageA(1, 1);
  __builtin_amdgcn_sched_barrier(0);
  asm volatile("s_waitcnt vmcnt(2)" ::: "memory");
  __builtin_amdgcn_s_barrier();

  int ca = 0;  // kt % 3 (A buf of current kt)
#pragma unroll 1
  for (int kt = 0; kt < NKS; ++kt) {
    // issue order matters for the vmcnt ledger: B(kt+1) then A(kt+2).
    if (kt + 1 < NKS) stageB(kt + 1, (kt + 1) & 1);
    if (kt + 2 < NKS) stageA(kt + 2, ca >= 1 ? ca - 1 : ca + 2);  // (kt+2)%3

    const int aOff = ca * 4096;
    const int bOff = 12288 + (kt & 1) * 4096;
    s16x8 af[4], bf[4];
#pragma unroll
    for (int m = 0; m < 4; ++m)
      af[m] = *(const s16x8*)(LF + aOff + aRel + m * 512);
#pragma unroll
    for (int n = 0; n < 4; ++n)
      bf[n] = *(const s16x8*)(LF + bOff + bRel + n * 512);
#pragma unroll
    for (int m = 0; m < 4; ++m)
#pragma unroll
      for (int n = 0; n < 4; ++n)
        acc[m][n] = __builtin_amdgcn_mfma_f32_16x16x32_bf16(af[m], bf[n],
                                                            acc[m][n], 0, 0, 0);
    __builtin_amdgcn_sched_barrier(0);
    // Ledger at fence: A(kt+1)2 | B(kt+1)2 | A(kt+2)2 -> vmcnt(2) covers
    // exactly {A(kt+1), B(kt+1)}; A(kt+2) stays in flight ~2 iters.
    if (kt <= NKS - 3) {
      asm volatile("s_waitcnt vmcnt(2)" ::: "memory");
    } else if (kt == NKS - 2) {
      asm volatile("s_waitcnt vmcnt(0)" ::: "memory");
    }
    __builtin_amdgcn_s_barrier();
    ca = ca == 2 ? 0 : ca + 1;
  }

  // ---- Epilogue: fold tile into row-i sums and (off-diag) row-j sums.
  float* rp = (float*)(void*)LF;  // 128 rpos | 128 rneg | 128 cpos | 128 cneg
  float* rn = rp + 128;
  float* cp = rn + 128;
  float* cn = cp + 128;
  rp[tid] = 0.0f;
  rp[tid + 256] = 0.0f;
  __syncthreads();

  const float C0 = -5.0f + 1e-7f;  // s = 5g - 5 + 1e-7 (static shift S=10)
  int lj4[4], gj4[4];
#pragma unroll
  for (int n = 0; n < 4; ++n) {
    gj4[n] = j0 + wc * 64 + n * 16 + c16;
    lj4[n] = labels[gj4[n]];
  }
  float psj[4] = {0.0f, 0.0f, 0.0f, 0.0f};
  float nsj[4] = {0.0f, 0.0f, 0.0f, 0.0f};
#pragma unroll
  for (int m = 0; m < 4; ++m) {
#pragma unroll
    for (int r = 0; r < 4; ++r) {
      const int lrow = wr * 64 + m * 16 + quad * 4 + r;
      const int gi = i0 + lrow;
      const int li = labels[gi];
      float psi = 0.0f, nsi = 0.0f;
#pragma unroll
      for (int n = 0; n < 4; ++n) {
        const float g2 = acc[m][n][r];
        const float sv = fmaf(g2, 5.0f, C0);
        const float ev = __expf(sv);
        const bool same = (li == lj4[n]);
        const bool ok = same && (gi != gj4[n]);
        psi += ok ? sv : 0.0f;
        nsi += same ? 0.0f : ev;
        psj[n] += ok ? sv : 0.0f;  // col-side accumulation (over m,r)
        nsj[n] += same ? 0.0f : ev;
      }
#pragma unroll
      for (int s = 1; s < 16; s <<= 1) {  // reduce over the 16 c16 lanes
        psi += __shfl_xor(psi, s);
        nsi += __shfl_xor(nsi, s);
      }
      if (c16 == 0) {
        atomicAdd(&rp[lrow], psi);
        atomicAdd(&rn[lrow], nsi);
      }
    }
  }
  if (!diag) {  // col-side: reduce over quad groups, cross-wr via LDS atomics
#pragma unroll
    for (int n = 0; n < 4; ++n) {
      float p = psj[n], q = nsj[n];
      p += __shfl_xor(p, 16); p += __shfl_xor(p, 32);
      q += __shfl_xor(q, 16); q += __shfl_xor(q, 32);
      if (quad == 0) {
        atomicAdd(&cp[wc * 64 + n * 16 + c16], p);
        atomicAdd(&cn[wc * 64 + n * 16 + c16], q);
      }
    }
  }
  __syncthreads();
  if (tid < 128) {
    atomicAdd(&row_pos[i0 + tid], rp[tid]);
    atomicAdd(&row_neg[i0 + tid], rn[tid]);
  } else if (!diag) {
    atomicAdd(&row_pos[j0 + tid - 128], cp[tid - 128]);
    atomicAdd(&row_neg[j0 + tid - 128], cn[tid - 128]);
  }
}

// LDS label histogram + loss reduction, 1024 threads (8 strided iters).
__global__ void __launch_bounds__(1024) k_final(
    const float* __restrict__ row_pos, const float* __restrict__ row_neg,
    const int* __restrict__ labels, float* __restrict__ out) {
  __shared__ int hcnt[NCLS];
  __shared__ float ssum[16];
  __shared__ float scnt[16];
  const int tid = threadIdx.x;
  if (tid < NCLS) hcnt[tid] = 0;
  __syncthreads();
  for (int i = tid; i < NROW; i += 1024) atomicAdd(&hcnt[labels[i]], 1);
  __syncthreads();
  float lsum = 0.0f, lcnt = 0.0f;
  for (int i = tid; i < NROW; i += 1024) {
    const float c = (float)(hcnt[labels[i]] - 1);
    const float pos = row_pos[i] / (c + 1e-8f);
    const float loss = -pos + logf(row_neg[i] + 1e-8f);
    if (loss > 0.0f) { lsum += loss; lcnt += 1.0f; }
  }
#pragma unroll
  for (int m = 1; m < 64; m <<= 1) {
    lsum += __shfl_xor(lsum, m);
    lcnt += __shfl_xor(lcnt, m);
  }
  if ((tid & 63) == 0) { ssum[tid >> 6] = lsum; scnt[tid >> 6] = lcnt; }
  __syncthreads();
  if (tid == 0) {
    float S = 0.0f, C = 0.0f;
#pragma unroll
    for (int w = 0; w < 16; ++w) { S += ssum[w]; C += scnt[w]; }
    out[0] = S / (C + 1e-8f);
  }
}

extern "C" void kernel_launch(void* const* d_in, const int* in_sizes, int n_in,
                              void* d_out, int out_size, void* d_ws, size_t ws_size,
                              hipStream_t stream) {
  const float* reps = (const float*)d_in[0];
  const int* labels = (const int*)d_in[1];
  float* out = (float*)d_out;
  char* ws = (char*)d_ws;
  // ws layout: Rb (bf16 normalized reps, 8 MiB) | row_pos | row_neg
  unsigned short* Rb = (unsigned short*)ws;
  float* row_pos = (float*)(ws + (size_t)NROW * DDIM * 2);
  float* row_neg = row_pos + NROW;

  k_prep<<<NROW / 8, 256, 0, stream>>>(reps, row_pos, Rb);
  k_row<<<NTRI, 256, 0, stream>>>(Rb, labels, row_pos, row_neg);
  k_final<<<1, 1024, 0, stream>>>(row_pos, row_neg, labels, out);
  (void)in_sizes; (void)n_in; (void)out_size; (void)ws_size;
}